// Round 1
// baseline (612.880 us; speedup 1.0000x reference)
//
#include <hip/hip_runtime.h>

#define NKW   65536
#define NDOC  65536
#define NSEG  131072          // kw counters then doc counters
#define NE    1048576

// ---------------- workspace layout (bytes) ----------------
#define SZ_BUF   33554432ull            // 65536*128*4
#define CSR_OFF  67108864ull            // 2*NE ints = 8 MB
#define CNT_OFF  75497472ull            // NSEG ints
#define FILL_OFF 76021760ull            // NSEG ints
#define SUMS_OFF 76546048ull            // 512 ints (pad 4 KB)
#define OFF_OFF  76550144ull            // NSEG ints
#define DIS_OFF  77074432ull            // NSEG floats

// ---------------- CSR build ----------------
__global__ void hist_k(const int* __restrict__ src, const int* __restrict__ dst,
                       int* __restrict__ cnt) {
    int e = blockIdx.x * 256 + threadIdx.x;
    atomicAdd(&cnt[src[e]], 1);   // kw out-degree
    atomicAdd(&cnt[dst[e]], 1);   // doc in-degree (dst already NKW+d)
}

__global__ void scan1_k(const int* __restrict__ cnt, int* __restrict__ off,
                        int* __restrict__ sums) {
    __shared__ int s[256];
    int tid = threadIdx.x;
    int i = blockIdx.x * 256 + tid;
    int v = cnt[i];
    s[tid] = v;
    __syncthreads();
    #pragma unroll
    for (int d = 1; d < 256; d <<= 1) {
        int t = (tid >= d) ? s[tid - d] : 0;
        __syncthreads();
        s[tid] += t;
        __syncthreads();
    }
    off[i] = s[tid] - v;                 // exclusive within block
    if (tid == 255) sums[blockIdx.x] = s[255];
}

__global__ void scan2_k(int* __restrict__ sums) {
    __shared__ int s[512];
    int tid = threadIdx.x;
    int v = sums[tid];
    s[tid] = v;
    __syncthreads();
    for (int d = 1; d < 512; d <<= 1) {
        int t = (tid >= d) ? s[tid - d] : 0;
        __syncthreads();
        s[tid] += t;
        __syncthreads();
    }
    sums[tid] = s[tid] - v;              // exclusive block offsets
}

__global__ void scan3_k(const int* __restrict__ cnt, int* __restrict__ off,
                        const int* __restrict__ sums, float* __restrict__ dis) {
    int i = blockIdx.x * 256 + threadIdx.x;
    off[i] += sums[blockIdx.x];
    dis[i] = rsqrtf((float)(cnt[i] + 1));   // deg includes self-loop
}

__global__ void scatter_k(const int* __restrict__ src, const int* __restrict__ dst,
                          const int* __restrict__ off, int* __restrict__ fill,
                          int* __restrict__ csr) {
    int e = blockIdx.x * 256 + threadIdx.x;
    int s = src[e], d = dst[e];
    int p = off[s] + atomicAdd(&fill[s], 1);
    csr[p] = d - NKW;                    // kw segment stores local doc idx
    int q = off[d] + atomicAdd(&fill[d], 1);
    csr[q] = s;                          // doc segment stores kw idx
}

// ---------------- neighborhood aggregation ----------------
// 8 rows per block, 32 lanes per row, float4 columns (512 B contiguous per edge)
template<bool KW_SIDE>
__global__ __launch_bounds__(256) void agg_k(
        const int* __restrict__ off, const int* __restrict__ cnt,
        const int* __restrict__ csr, const float* __restrict__ gsrc,
        const float* __restrict__ h0, const float* __restrict__ dis,
        float* __restrict__ outb) {
    int r    = blockIdx.x * 8 + (threadIdx.x >> 5);
    int lane = threadIdx.x & 31;
    int seg  = KW_SIDE ? r : (NKW + r);
    int st = off[seg];
    int n  = cnt[seg];
    const float4* g4 = (const float4*)gsrc;
    float4 acc = make_float4(0.f, 0.f, 0.f, 0.f);
    for (int i = 0; i < n; ++i) {
        int nb = csr[st + i];
        float4 v = g4[(size_t)nb * 32 + lane];
        acc.x += v.x; acc.y += v.y; acc.z += v.z; acc.w += v.w;
    }
    if (KW_SIDE) {
        // tmp = dk*sum + dk^2*h0 = dk*(sum + dk*h0)
        float dk = dis[r];
        float4 h = ((const float4*)h0)[(size_t)r * 32 + lane];
        acc.x = dk * (acc.x + dk * h.x);
        acc.y = dk * (acc.y + dk * h.y);
        acc.z = dk * (acc.z + dk * h.z);
        acc.w = dk * (acc.w + dk * h.w);
    }
    ((float4*)outb)[(size_t)r * 32 + lane] = acc;
}

// ---------------- tiled fp32 GEMM: C[M,128] = op(A[M,K] @ W[K,128] + b) ----------------
// block = 256 threads, 64-row tile, each thread 8 rows x 4 cols.
// A staged fully to LDS before any store -> in-place (C==A) is safe.
template<int K, bool RELU, bool ROWSCALE>
__global__ __launch_bounds__(256) void gemm_k(
        const float* A, const float* __restrict__ W,
        const float* __restrict__ bias, const float* __restrict__ rowscale,
        float* C) {
    __shared__ float As[64 * K];
    const int tid  = threadIdx.x;
    const int row0 = blockIdx.x * 64;

    constexpr int NV = 64 * K / 4;
    for (int idx = tid; idx < NV; idx += 256) {
        int row = idx / (K / 4);
        int c4  = idx % (K / 4);
        float4 v = *(const float4*)&A[(size_t)(row0 + row) * K + c4 * 4];
        if (ROWSCALE) {
            float sc = rowscale[row0 + row];
            v.x *= sc; v.y *= sc; v.z *= sc; v.w *= sc;
        }
        *(float4*)&As[row * K + c4 * 4] = v;
    }
    __syncthreads();

    const int tx = tid & 31;     // 4-col group (covers 128 cols)
    const int ty = tid >> 5;     // 8-row group (covers 64 rows)
    float acc[8][4];
    #pragma unroll
    for (int i = 0; i < 8; ++i)
        #pragma unroll
        for (int j = 0; j < 4; ++j) acc[i][j] = 0.f;

    for (int k4 = 0; k4 < K / 4; ++k4) {
        float4 w0 = *(const float4*)&W[(k4 * 4 + 0) * 128 + tx * 4];
        float4 w1 = *(const float4*)&W[(k4 * 4 + 1) * 128 + tx * 4];
        float4 w2 = *(const float4*)&W[(k4 * 4 + 2) * 128 + tx * 4];
        float4 w3 = *(const float4*)&W[(k4 * 4 + 3) * 128 + tx * 4];
        #pragma unroll
        for (int i = 0; i < 8; ++i) {
            float4 a = *(const float4*)&As[(ty * 8 + i) * K + k4 * 4];
            acc[i][0] += a.x * w0.x + a.y * w1.x + a.z * w2.x + a.w * w3.x;
            acc[i][1] += a.x * w0.y + a.y * w1.y + a.z * w2.y + a.w * w3.y;
            acc[i][2] += a.x * w0.z + a.y * w1.z + a.z * w2.z + a.w * w3.z;
            acc[i][3] += a.x * w0.w + a.y * w1.w + a.z * w2.w + a.w * w3.w;
        }
    }

    float4 b4 = *(const float4*)&bias[tx * 4];
    #pragma unroll
    for (int i = 0; i < 8; ++i) {
        float4 o;
        o.x = acc[i][0] + b4.x;
        o.y = acc[i][1] + b4.y;
        o.z = acc[i][2] + b4.z;
        o.w = acc[i][3] + b4.w;
        if (RELU) {
            o.x = fmaxf(o.x, 0.f); o.y = fmaxf(o.y, 0.f);
            o.z = fmaxf(o.z, 0.f); o.w = fmaxf(o.w, 0.f);
        }
        *(float4*)&C[(size_t)(row0 + ty * 8 + i) * 128 + tx * 4] = o;
    }
}

// ---------------- final gate: out_doc *= xf * xt ----------------
__global__ void mul_k(float* __restrict__ outdoc, const float* __restrict__ xf,
                      const float* __restrict__ xt) {
    size_t i = (size_t)blockIdx.x * 256 + threadIdx.x;   // float4 index
    float4 o = ((const float4*)outdoc)[i];
    float4 f = ((const float4*)xf)[i];
    float4 t = ((const float4*)xt)[i];
    o.x *= f.x * t.x; o.y *= f.y * t.y; o.z *= f.z * t.z; o.w *= f.w * t.w;
    ((float4*)outdoc)[i] = o;
}

extern "C" void kernel_launch(void* const* d_in, const int* in_sizes, int n_in,
                              void* d_out, int out_size, void* d_ws, size_t ws_size,
                              hipStream_t stream) {
    const float* Xn  = (const float*)d_in[0];
    const float* Xfb = (const float*)d_in[1];
    const float* Xt  = (const float*)d_in[2];
    const int*   e01 = (const int*)d_in[3];      // [2, E]: row0 src(kw), row1 dst(NKW+doc)
    const float* W0  = (const float*)d_in[6];
    const float* b0  = (const float*)d_in[7];
    const float* Wg1 = (const float*)d_in[8];
    const float* bg1 = (const float*)d_in[9];
    const float* Wg2 = (const float*)d_in[10];
    const float* bg2 = (const float*)d_in[11];
    const float* Wf1 = (const float*)d_in[12];
    const float* bf1 = (const float*)d_in[13];
    const float* Wf2 = (const float*)d_in[14];
    const float* bf2 = (const float*)d_in[15];
    const float* Wt1 = (const float*)d_in[16];
    const float* bt1 = (const float*)d_in[17];
    const float* Wt2 = (const float*)d_in[18];
    const float* bt2 = (const float*)d_in[19];

    float* out = (float*)d_out;
    char*  ws  = (char*)d_ws;
    float* bufA = (float*)ws;                       // h0, later xf1/xf
    float* bufB = (float*)(ws + SZ_BUF);            // agg_doc / tmp_kw, later xt1/xt
    int*   csr  = (int*)(ws + CSR_OFF);
    int*   cnt  = (int*)(ws + CNT_OFF);
    int*   fill = (int*)(ws + FILL_OFF);
    int*   sums = (int*)(ws + SUMS_OFF);
    int*   off  = (int*)(ws + OFF_OFF);
    float* dis  = (float*)(ws + DIS_OFF);

    const int* src = e01;
    const int* dst = e01 + NE;
    float* xdoc = out + (size_t)NKW * 128;

    // zero cnt + fill + sums (contiguous region)
    hipMemsetAsync(cnt, 0, 524288 + 524288 + 4096, stream);

    // CSR build
    hist_k   <<<NE / 256, 256, 0, stream>>>(src, dst, cnt);
    scan1_k  <<<NSEG / 256, 256, 0, stream>>>(cnt, off, sums);
    scan2_k  <<<1, 512, 0, stream>>>(sums);
    scan3_k  <<<NSEG / 256, 256, 0, stream>>>(cnt, off, sums, dis);
    scatter_k<<<NE / 256, 256, 0, stream>>>(src, dst, off, fill, csr);

    // layer 0: h0 = relu(Xn[:NKW] @ W0 + b0)
    gemm_k<128, true, false><<<1024, 256, 0, stream>>>(Xn, W0, b0, nullptr, bufA);

    // layer 1: agg_doc = sum h0[src]; xdoc = relu((dis_doc * agg) @ Wg1 + bg1)
    agg_k<false><<<NDOC / 8, 256, 0, stream>>>(off, cnt, csr, bufA, nullptr, nullptr, bufB);
    gemm_k<128, true, true><<<1024, 256, 0, stream>>>(bufB, Wg1, bg1, dis + NKW, xdoc);

    // layer 2: tmp = dk*(sum xdoc[d] + dk*h0); out_kw = relu(tmp @ Wg2 + bg2)
    agg_k<true><<<NKW / 8, 256, 0, stream>>>(off, cnt, csr, xdoc, bufA, dis, bufB);
    gemm_k<128, true, false><<<1024, 256, 0, stream>>>(bufB, Wg2, bg2, nullptr, out);

    // gates: xf = relu(Xfb@Wf1+bf1)@Wf2+bf2 ; xt = relu(Xt@Wt1+bt1)@Wt2+bt2
    gemm_k<16, true, false><<<1024, 256, 0, stream>>>(Xfb, Wf1, bf1, nullptr, bufA);
    gemm_k<8,  true, false><<<1024, 256, 0, stream>>>(Xt,  Wt1, bt1, nullptr, bufB);
    gemm_k<128, false, false><<<1024, 256, 0, stream>>>(bufA, Wf2, bf2, nullptr, bufA); // in-place
    gemm_k<128, false, false><<<1024, 256, 0, stream>>>(bufB, Wt2, bt2, nullptr, bufB); // in-place

    // out_doc = xdoc * xf * xt
    mul_k<<<(NDOC * 128 / 4) / 256, 256, 0, stream>>>(xdoc, bufA, bufB);
}

// Round 2
// 399.945 us; speedup vs baseline: 1.5324x; 1.5324x over previous
//
#include <hip/hip_runtime.h>

#define NKW   65536
#define NDOC  65536
#define NSEG  131072          // kw counters then doc counters
#define NE    1048576

typedef unsigned long long u64;
typedef unsigned short     u16;
typedef unsigned int       u32;

typedef __attribute__((ext_vector_type(8))) short short8;   // 8 bf16 (4 VGPRs)
typedef __attribute__((ext_vector_type(4))) float f32x4;    // MFMA acc

union U8 { short8 v; u64 u[2]; short s[8]; };

__device__ __forceinline__ u16 f2bf(float f) {              // RNE f32->bf16
    u32 u = __builtin_bit_cast(u32, f);
    u = (u + 0x7fffu + ((u >> 16) & 1u)) >> 16;
    return (u16)u;
}
__device__ __forceinline__ float bf2f(u16 h) {
    return __builtin_bit_cast(float, (u32)h << 16);
}

// ---------------- workspace layout (bytes) ----------------
// bufA 16MB | bufB 16MB | bufC 16MB | wfrag 224KB | csr 8MB | cnt/fill/sums | off | dis
#define BUFA_OFF 0ull
#define BUFB_OFF 16777216ull
#define BUFC_OFF 33554432ull
#define WF_OFF   50331648ull            // 7 * 32KB fragment-packed weights
#define CSR_OFF  51380224ull            // 2*NE ints = 8 MB
#define CNT_OFF  59768832ull            // NSEG ints
#define FILL_OFF 60293120ull            // NSEG ints
#define SUMS_OFF 60817408ull            // 512 ints
#define OFF_OFF  60821504ull            // NSEG ints
#define DIS_OFF  61345792ull            // NSEG floats

// ---------------- CSR build ----------------
__global__ void hist_k(const int* __restrict__ src, const int* __restrict__ dst,
                       int* __restrict__ cnt) {
    int e = blockIdx.x * 256 + threadIdx.x;
    atomicAdd(&cnt[src[e]], 1);   // kw out-degree
    atomicAdd(&cnt[dst[e]], 1);   // doc in-degree (dst already NKW+d)
}

__global__ void scan1_k(const int* __restrict__ cnt, int* __restrict__ off,
                        int* __restrict__ sums) {
    __shared__ int s[256];
    int tid = threadIdx.x;
    int i = blockIdx.x * 256 + tid;
    int v = cnt[i];
    s[tid] = v;
    __syncthreads();
    #pragma unroll
    for (int d = 1; d < 256; d <<= 1) {
        int t = (tid >= d) ? s[tid - d] : 0;
        __syncthreads();
        s[tid] += t;
        __syncthreads();
    }
    off[i] = s[tid] - v;
    if (tid == 255) sums[blockIdx.x] = s[255];
}

__global__ void scan2_k(int* __restrict__ sums) {
    __shared__ int s[512];
    int tid = threadIdx.x;
    int v = sums[tid];
    s[tid] = v;
    __syncthreads();
    for (int d = 1; d < 512; d <<= 1) {
        int t = (tid >= d) ? s[tid - d] : 0;
        __syncthreads();
        s[tid] += t;
        __syncthreads();
    }
    sums[tid] = s[tid] - v;
}

__global__ void scan3_k(const int* __restrict__ cnt, int* __restrict__ off,
                        const int* __restrict__ sums, float* __restrict__ dis) {
    int i = blockIdx.x * 256 + threadIdx.x;
    off[i] += sums[blockIdx.x];
    dis[i] = rsqrtf((float)(cnt[i] + 1));
}

__global__ void scatter_k(const int* __restrict__ src, const int* __restrict__ dst,
                          const int* __restrict__ off, int* __restrict__ fill,
                          int* __restrict__ csr) {
    int e = blockIdx.x * 256 + threadIdx.x;
    int s = src[e], d = dst[e];
    int p = off[s] + atomicAdd(&fill[s], 1);
    csr[p] = d - NKW;
    int q = off[d] + atomicAdd(&fill[d], 1);
    csr[q] = s;
}

// ---------------- weight fragment pre-pack (fp32 [K][128] -> bf16 MFMA B-frags) ----
// layout: out[m*2048 + (kc*8+ct)*64 + lane] = short8 with elems i:
//   k = kc*32 + 4*(lane>>4) + (i&3) + 16*(i>>2), col = ct*16 + (lane&15)
struct PrepArgs { const float* w[7]; int K[7]; };

__global__ void prepw_k(PrepArgs pa, short8* __restrict__ outb) {
    int m  = blockIdx.x >> 5;       // matrix 0..6
    int bk = blockIdx.x & 31;       // kc*8+ct
    int kc = bk >> 3, ct = bk & 7;
    int l  = threadIdx.x;           // 0..63
    int K  = pa.K[m];
    const float* W = pa.w[m];
    U8 o;
    #pragma unroll
    for (int i = 0; i < 8; ++i) {
        int k   = kc * 32 + 4 * (l >> 4) + (i & 3) + 16 * (i >> 2);
        int col = ct * 16 + (l & 15);
        float v = (k < K) ? W[(size_t)k * 128 + col] : 0.f;
        o.s[i] = (short)f2bf(v);
    }
    outb[(size_t)m * 2048 + bk * 64 + l] = o.v;
}

// ---------------- MFMA GEMM: C[65536,128] = op(A[65536,K] @ W[K,128] + b) --------
// 256 thr = 4 waves; wave w owns rows blk*64 + w*16 .. +15; 8 col-tiles of 16.
// A loaded per-lane direct from global (fp32->bf16 convert or raw bf16).
// In-place safe (each block reads only its own rows, stores after all MFMAs).
template<int K, bool AF32, bool RELU, bool OUTF32>
__global__ __launch_bounds__(256) void mgemm_k(
        const void* __restrict__ Av, const short8* __restrict__ wf,
        const float* __restrict__ bias, void* __restrict__ Cv) {
    const int tid = threadIdx.x;
    const int w  = tid >> 6;
    const int l  = tid & 63;
    const int lr = l & 15;
    const int q  = l >> 4;
    const int row = blockIdx.x * 64 + w * 16 + lr;
    constexpr int NKC = (K + 31) / 32;

    f32x4 acc[8];
    #pragma unroll
    for (int ct = 0; ct < 8; ++ct) acc[ct] = (f32x4){0.f, 0.f, 0.f, 0.f};

    #pragma unroll
    for (int kc = 0; kc < NKC; ++kc) {
        U8 a;
        const int kb = kc * 32 + 4 * q;
        if (AF32) {
            const float* A = (const float*)Av + (size_t)row * K;
            f32x4 lo = (f32x4){0.f,0.f,0.f,0.f}, hi = (f32x4){0.f,0.f,0.f,0.f};
            if (kb < K)      lo = *(const f32x4*)(A + kb);
            if (kb + 16 < K) hi = *(const f32x4*)(A + kb + 16);
            #pragma unroll
            for (int i = 0; i < 4; ++i) {
                a.s[i]     = (short)f2bf(lo[i]);
                a.s[4 + i] = (short)f2bf(hi[i]);
            }
        } else {
            const u16* A = (const u16*)Av + (size_t)row * K;
            a.u[0] = (kb < K)      ? *(const u64*)(A + kb)      : 0ull;
            a.u[1] = (kb + 16 < K) ? *(const u64*)(A + kb + 16) : 0ull;
        }
        #pragma unroll
        for (int ct = 0; ct < 8; ++ct)
            acc[ct] = __builtin_amdgcn_mfma_f32_16x16x32_bf16(
                          a.v, wf[(kc * 8 + ct) * 64 + l], acc[ct], 0, 0, 0);
    }

    // C/D layout (HW-verified): col = lane&15, row = (lane>>4)*4 + reg
    const int orow0 = blockIdx.x * 64 + w * 16 + 4 * q;
    #pragma unroll
    for (int ct = 0; ct < 8; ++ct) {
        const int col = ct * 16 + lr;
        const float b = bias[col];
        #pragma unroll
        for (int r = 0; r < 4; ++r) {
            float v = acc[ct][r] + b;
            if (RELU) v = fmaxf(v, 0.f);
            if (OUTF32) ((float*)Cv)[(size_t)(orow0 + r) * 128 + col] = v;
            else        ((u16*)Cv)[(size_t)(orow0 + r) * 128 + col] = f2bf(v);
        }
    }
}

// ---------------- bf16 neighborhood aggregation ----------------
// 8 rows/block, 32 lanes/row, 4 bf16 (8B) per lane; fp32 accumulate; dis folded in.
template<bool KW_SIDE>
__global__ __launch_bounds__(256) void aggb_k(
        const int* __restrict__ off, const int* __restrict__ cnt,
        const int* __restrict__ csr, const u16* __restrict__ gsrc,
        const u16* __restrict__ h0, const float* __restrict__ dis,
        u16* __restrict__ outb) {
    int r    = blockIdx.x * 8 + (threadIdx.x >> 5);
    int lane = threadIdx.x & 31;
    int seg  = KW_SIDE ? r : (NKW + r);
    int st = off[seg];
    int n  = cnt[seg];
    float a0 = 0.f, a1 = 0.f, a2 = 0.f, a3 = 0.f;
    #define ACC4(vv) { a0 += bf2f((u16)(vv)); a1 += bf2f((u16)((vv) >> 16)); \
                       a2 += bf2f((u16)((vv) >> 32)); a3 += bf2f((u16)((vv) >> 48)); }
    int i = 0;
    for (; i + 4 <= n; i += 4) {                  // 4 gathers in flight
        int nb0 = csr[st + i], nb1 = csr[st + i + 1];
        int nb2 = csr[st + i + 2], nb3 = csr[st + i + 3];
        u64 v0 = *(const u64*)(gsrc + (size_t)nb0 * 128 + lane * 4);
        u64 v1 = *(const u64*)(gsrc + (size_t)nb1 * 128 + lane * 4);
        u64 v2 = *(const u64*)(gsrc + (size_t)nb2 * 128 + lane * 4);
        u64 v3 = *(const u64*)(gsrc + (size_t)nb3 * 128 + lane * 4);
        ACC4(v0) ACC4(v1) ACC4(v2) ACC4(v3)
    }
    for (; i < n; ++i) {
        int nb = csr[st + i];
        u64 v = *(const u64*)(gsrc + (size_t)nb * 128 + lane * 4);
        ACC4(v)
    }
    #undef ACC4
    float dk = dis[seg];
    if (KW_SIDE) {   // t = dk*(sum + dk*h0)
        u64 h = *(const u64*)(h0 + (size_t)r * 128 + lane * 4);
        a0 = dk * (a0 + dk * bf2f((u16)h));
        a1 = dk * (a1 + dk * bf2f((u16)(h >> 16)));
        a2 = dk * (a2 + dk * bf2f((u16)(h >> 32)));
        a3 = dk * (a3 + dk * bf2f((u16)(h >> 48)));
    } else {         // pre-scale by dis_doc (commutes with the GEMM)
        a0 *= dk; a1 *= dk; a2 *= dk; a3 *= dk;
    }
    u64 ov = (u64)f2bf(a0) | ((u64)f2bf(a1) << 16) |
             ((u64)f2bf(a2) << 32) | ((u64)f2bf(a3) << 48);
    *(u64*)(outb + (size_t)r * 128 + lane * 4) = ov;
}

// ---------------- final gate: out_doc = xdoc * xf * xt (bf16 in, fp32 out) -------
__global__ void mulb_k(const u16* __restrict__ xd, const u16* __restrict__ xf,
                       const u16* __restrict__ xt, float* __restrict__ out) {
    size_t i = (size_t)blockIdx.x * 256 + threadIdx.x;    // group of 4 elems
    u64 d = ((const u64*)xd)[i];
    u64 f = ((const u64*)xf)[i];
    u64 t = ((const u64*)xt)[i];
    float4 o;
    o.x = bf2f((u16)d)         * bf2f((u16)f)         * bf2f((u16)t);
    o.y = bf2f((u16)(d >> 16)) * bf2f((u16)(f >> 16)) * bf2f((u16)(t >> 16));
    o.z = bf2f((u16)(d >> 32)) * bf2f((u16)(f >> 32)) * bf2f((u16)(t >> 32));
    o.w = bf2f((u16)(d >> 48)) * bf2f((u16)(f >> 48)) * bf2f((u16)(t >> 48));
    ((float4*)out)[i] = o;
}

extern "C" void kernel_launch(void* const* d_in, const int* in_sizes, int n_in,
                              void* d_out, int out_size, void* d_ws, size_t ws_size,
                              hipStream_t stream) {
    const float* Xn  = (const float*)d_in[0];
    const float* Xfb = (const float*)d_in[1];
    const float* Xt  = (const float*)d_in[2];
    const int*   e01 = (const int*)d_in[3];      // [2, E]: row0 src(kw), row1 dst(NKW+doc)
    const float* W0  = (const float*)d_in[6];
    const float* b0  = (const float*)d_in[7];
    const float* Wg1 = (const float*)d_in[8];
    const float* bg1 = (const float*)d_in[9];
    const float* Wg2 = (const float*)d_in[10];
    const float* bg2 = (const float*)d_in[11];
    const float* Wf1 = (const float*)d_in[12];
    const float* bf1 = (const float*)d_in[13];
    const float* Wf2 = (const float*)d_in[14];
    const float* bf2 = (const float*)d_in[15];
    const float* Wt1 = (const float*)d_in[16];
    const float* bt1 = (const float*)d_in[17];
    const float* Wt2 = (const float*)d_in[18];
    const float* bt2 = (const float*)d_in[19];

    float* out = (float*)d_out;
    char*  ws  = (char*)d_ws;
    u16*   bufA = (u16*)(ws + BUFA_OFF);     // h0 bf16, later xf
    u16*   bufB = (u16*)(ws + BUFB_OFF);     // agg out bf16, later xt
    u16*   bufC = (u16*)(ws + BUFC_OFF);     // xdoc bf16
    short8* wfb = (short8*)(ws + WF_OFF);
    int*   csr  = (int*)(ws + CSR_OFF);
    int*   cnt  = (int*)(ws + CNT_OFF);
    int*   fill = (int*)(ws + FILL_OFF);
    int*   sums = (int*)(ws + SUMS_OFF);
    int*   off  = (int*)(ws + OFF_OFF);
    float* dis  = (float*)(ws + DIS_OFF);

    const int* src = e01;
    const int* dst = e01 + NE;

    // weight pre-pack (independent of CSR)
    PrepArgs pa;
    pa.w[0] = W0;  pa.K[0] = 128;
    pa.w[1] = Wg1; pa.K[1] = 128;
    pa.w[2] = Wg2; pa.K[2] = 128;
    pa.w[3] = Wf1; pa.K[3] = 16;
    pa.w[4] = Wf2; pa.K[4] = 128;
    pa.w[5] = Wt1; pa.K[5] = 8;
    pa.w[6] = Wt2; pa.K[6] = 128;
    prepw_k<<<224, 64, 0, stream>>>(pa, wfb);

    // CSR build
    hipMemsetAsync(cnt, 0, 1052672, stream);   // cnt + fill + sums
    hist_k   <<<NE / 256, 256, 0, stream>>>(src, dst, cnt);
    scan1_k  <<<NSEG / 256, 256, 0, stream>>>(cnt, off, sums);
    scan2_k  <<<1, 512, 0, stream>>>(sums);
    scan3_k  <<<NSEG / 256, 256, 0, stream>>>(cnt, off, sums, dis);
    scatter_k<<<NE / 256, 256, 0, stream>>>(src, dst, off, fill, csr);

    // layer 0: h0 = relu(Xn[:NKW] @ W0 + b0)  (fp32 in, bf16 out)
    mgemm_k<128, true,  true,  false><<<1024, 256, 0, stream>>>(Xn, wfb + 0*2048, b0, bufA);

    // layer 1: aggB = dis_doc * sum h0[src] ; xdoc = relu(aggB @ Wg1 + bg1)
    aggb_k<false><<<NDOC / 8, 256, 0, stream>>>(off, cnt, csr, bufA, nullptr, dis, bufB);
    mgemm_k<128, false, true,  false><<<1024, 256, 0, stream>>>(bufB, wfb + 1*2048, bg1, bufC);

    // layer 2: aggB = dk*(sum xdoc[d] + dk*h0) ; out_kw = relu(aggB @ Wg2 + bg2) fp32
    aggb_k<true><<<NKW / 8, 256, 0, stream>>>(off, cnt, csr, bufC, bufA, dis, bufB);
    mgemm_k<128, false, true,  true ><<<1024, 256, 0, stream>>>(bufB, wfb + 2*2048, bg2, out);

    // gates (bufA free after layer-2 agg)
    mgemm_k<16,  true,  true,  false><<<1024, 256, 0, stream>>>(Xfb,  wfb + 3*2048, bf1, bufA);
    mgemm_k<128, false, false, false><<<1024, 256, 0, stream>>>(bufA, wfb + 4*2048, bf2, bufA); // in-place
    mgemm_k<8,   true,  true,  false><<<1024, 256, 0, stream>>>(Xt,   wfb + 5*2048, bt1, bufB);
    mgemm_k<128, false, false, false><<<1024, 256, 0, stream>>>(bufB, wfb + 6*2048, bt2, bufB); // in-place

    // out_doc = xdoc * xf * xt  (fp32 store)
    mulb_k<<<(NDOC * 128 / 4) / 256, 256, 0, stream>>>(bufC, bufA, bufB, out + (size_t)NKW * 128);
}

// Round 3
// 229.246 us; speedup vs baseline: 2.6735x; 1.7446x over previous
//
#include <hip/hip_runtime.h>

#define NKW   65536
#define NDOC  65536
#define NSEG  131072          // kw segs then doc segs
#define NE    1048576
#define CHUNK 4096            // edges per partition block
#define NBLK  (NE / CHUNK)    // 256

typedef unsigned long long u64;
typedef unsigned short     u16;
typedef unsigned int       u32;

typedef __attribute__((ext_vector_type(8))) short short8;   // 8 bf16 (4 VGPRs)
typedef __attribute__((ext_vector_type(4))) float f32x4;    // MFMA acc

union U8 { short8 v; u64 u[2]; short s[8]; };

__device__ __forceinline__ u16 f2bf(float f) {              // RNE f32->bf16
    u32 u = __builtin_bit_cast(u32, f);
    u = (u + 0x7fffu + ((u >> 16) & 1u)) >> 16;
    return (u16)u;
}
__device__ __forceinline__ float bf2f(u16 h) {
    return __builtin_bit_cast(float, (u32)h << 16);
}

// ---------------- workspace layout (bytes) ----------------
// bufA 16MB (pairs alias) | bufB 16MB | bufC 16MB | wfrag | csr 8MB | cnt | aux | off | dis
#define BUFA_OFF 0ull
#define BUFB_OFF 16777216ull
#define BUFC_OFF 33554432ull
#define WF_OFF   50331648ull            // 7 * 32KB fragment-packed weights
#define CSR_OFF  51380224ull            // 2*NE ints = 8 MB
#define CNT_OFF  59768832ull            // NSEG ints
#define AUX_OFF  60293120ull            // bhist[512] | bfill[512] | bbase[512]
#define OFF_OFF  60821504ull            // NSEG ints
#define DIS_OFF  61345792ull            // NSEG floats

// ---------------- CSR build (bucketed, write-local) ----------------
// Buckets: kw bucket b = s>>8 (0..255), doc bucket 256 + (d>>8).
// pairs pos space: kw buckets occupy [0,NE), doc buckets [NE,2NE).
// pair = (local_node(8b) << 16) | val(16b);  kw side val = doc idx, doc side val = kw idx.

__global__ __launch_bounds__(256) void bhist_k(const int* __restrict__ src,
                                               const int* __restrict__ dst,
                                               int* __restrict__ bhist) {
    __shared__ int h[512];
    int tid = threadIdx.x;
    for (int i = tid; i < 512; i += 256) h[i] = 0;
    __syncthreads();
    int e0 = blockIdx.x * CHUNK;
    for (int i = tid; i < CHUNK; i += 256) {
        int s = src[e0 + i];
        int d = dst[e0 + i] - NKW;
        atomicAdd(&h[s >> 8], 1);
        atomicAdd(&h[256 + (d >> 8)], 1);
    }
    __syncthreads();
    for (int i = tid; i < 512; i += 256)
        if (h[i]) atomicAdd(&bhist[i], h[i]);
}

__global__ void bscan_k(const int* __restrict__ bhist, int* __restrict__ bbase) {
    __shared__ int s[512];
    int tid = threadIdx.x;
    int v = bhist[tid];
    s[tid] = v;
    __syncthreads();
    for (int d = 1; d < 512; d <<= 1) {
        int t = (tid >= d) ? s[tid - d] : 0;
        __syncthreads();
        s[tid] += t;
        __syncthreads();
    }
    bbase[tid] = s[tid] - v;      // exclusive
}

__global__ __launch_bounds__(256) void part_k(const int* __restrict__ src,
                                              const int* __restrict__ dst,
                                              const int* __restrict__ bbase,
                                              int* __restrict__ bfill,
                                              u32* __restrict__ pairs) {
    __shared__ int h[512], sc[512], base[512];
    __shared__ u32 staged[2 * CHUNK];
    const int tid = threadIdx.x;
    for (int i = tid; i < 512; i += 256) h[i] = 0;
    __syncthreads();

    const int e0 = blockIdx.x * CHUNK;
    int se[16], de[16];
    #pragma unroll
    for (int j = 0; j < 16; ++j) {
        int e = e0 + tid + j * 256;           // coalesced
        se[j] = src[e];
        de[j] = dst[e] - NKW;
        atomicAdd(&h[se[j] >> 8], 1);
        atomicAdd(&h[256 + (de[j] >> 8)], 1);
    }
    __syncthreads();

    // inclusive scan of kw side h[0..255] -> sc[0..255]
    sc[tid] = h[tid];
    __syncthreads();
    for (int d = 1; d < 256; d <<= 1) {
        int t = (tid >= d) ? sc[tid - d] : 0;
        __syncthreads();
        sc[tid] += t;
        __syncthreads();
    }
    // inclusive scan of doc side h[256..511] -> sc[256..511]
    sc[256 + tid] = h[256 + tid];
    __syncthreads();
    for (int d = 1; d < 256; d <<= 1) {
        int t = (tid >= d) ? sc[256 + tid - d] : 0;
        __syncthreads();
        sc[256 + tid] += t;
        __syncthreads();
    }

    // reserve global runs (one atomic per bucket per block), make sc exclusive, reset h
    for (int i = tid; i < 512; i += 256) {
        base[i] = bbase[i] + atomicAdd(&bfill[i], h[i]);
        sc[i] -= h[i];
        h[i] = 0;
    }
    __syncthreads();

    // rank + stage in LDS (bucket-ordered)
    #pragma unroll
    for (int j = 0; j < 16; ++j) {
        int bk = se[j] >> 8;
        int r  = atomicAdd(&h[bk], 1);
        staged[sc[bk] + r] = ((u32)(se[j] & 255) << 16) | (u32)de[j];
        int bd = 256 + (de[j] >> 8);
        int r2 = atomicAdd(&h[bd], 1);
        staged[CHUNK + sc[bd] + r2] = ((u32)(de[j] & 255) << 16) | (u32)se[j];
    }
    __syncthreads();

    // copy out: each thread owns 2 buckets, sequential run writes
    for (int i = tid; i < 512; i += 256) {
        int n = h[i];
        int so = (i < 256 ? 0 : CHUNK) + sc[i];
        u32* dp = pairs + base[i];
        for (int j = 0; j < n; ++j) dp[j] = staged[so + j];
    }
}

__global__ __launch_bounds__(256) void build_k(const u32* __restrict__ pairs,
                                               const int* __restrict__ bbase,
                                               const int* __restrict__ bfill,
                                               int* __restrict__ off, int* __restrict__ cnt,
                                               float* __restrict__ dis, int* __restrict__ csr) {
    __shared__ int lcnt[256], lsc[256];
    const int b   = blockIdx.x;
    const int tid = threadIdx.x;
    const int start = bbase[b];
    const int size  = bfill[b];
    lcnt[tid] = 0;
    __syncthreads();
    for (int i = tid; i < size; i += 256)
        atomicAdd(&lcnt[(pairs[start + i] >> 16) & 255], 1);
    __syncthreads();
    // inclusive scan lcnt -> lsc
    lsc[tid] = lcnt[tid];
    __syncthreads();
    for (int d = 1; d < 256; d <<= 1) {
        int t = (tid >= d) ? lsc[tid - d] : 0;
        __syncthreads();
        lsc[tid] += t;
        __syncthreads();
    }
    const int myexc = lsc[tid] - lcnt[tid];
    const int seg = (b < 256) ? (b * 256 + tid) : (NKW + (b - 256) * 256 + tid);
    off[seg] = start + myexc;
    cnt[seg] = lcnt[tid];
    dis[seg] = rsqrtf((float)(lcnt[tid] + 1));
    lsc[tid]  = myexc;          // exclusive
    lcnt[tid] = 0;
    __syncthreads();
    // place values: writes confined to this bucket's contiguous csr slice
    for (int i = tid; i < size; i += 256) {
        u32 p = pairs[start + i];
        int key = (p >> 16) & 255;
        int r = atomicAdd(&lcnt[key], 1);
        csr[start + lsc[key] + r] = (int)(p & 0xFFFF);
    }
}

// ---------------- weight fragment pre-pack (fp32 [K][128] -> bf16 MFMA B-frags) ----
// layout: out[m*2048 + (kc*8+ct)*64 + lane] = short8 with elems i:
//   k = kc*32 + 4*(lane>>4) + (i&3) + 16*(i>>2), col = ct*16 + (lane&15)
struct PrepArgs { const float* w[7]; int K[7]; };

__global__ void prepw_k(PrepArgs pa, short8* __restrict__ outb) {
    int m  = blockIdx.x >> 5;       // matrix 0..6
    int bk = blockIdx.x & 31;       // kc*8+ct
    int kc = bk >> 3, ct = bk & 7;
    int l  = threadIdx.x;           // 0..63
    int K  = pa.K[m];
    const float* W = pa.w[m];
    U8 o;
    #pragma unroll
    for (int i = 0; i < 8; ++i) {
        int k   = kc * 32 + 4 * (l >> 4) + (i & 3) + 16 * (i >> 2);
        int col = ct * 16 + (l & 15);
        float v = (k < K) ? W[(size_t)k * 128 + col] : 0.f;
        o.s[i] = (short)f2bf(v);
    }
    outb[(size_t)m * 2048 + bk * 64 + l] = o.v;
}

// ---------------- MFMA GEMM: C[65536,128] = op(A[65536,K] @ W[K,128] + b) --------
// 256 thr = 4 waves; wave w owns rows blk*64 + w*16 .. +15; 8 col-tiles of 16.
template<int K, bool AF32, bool RELU, bool OUTF32>
__global__ __launch_bounds__(256) void mgemm_k(
        const void* __restrict__ Av, const short8* __restrict__ wf,
        const float* __restrict__ bias, void* __restrict__ Cv) {
    const int tid = threadIdx.x;
    const int w  = tid >> 6;
    const int l  = tid & 63;
    const int lr = l & 15;
    const int q  = l >> 4;
    const int row = blockIdx.x * 64 + w * 16 + lr;
    constexpr int NKC = (K + 31) / 32;

    f32x4 acc[8];
    #pragma unroll
    for (int ct = 0; ct < 8; ++ct) acc[ct] = (f32x4){0.f, 0.f, 0.f, 0.f};

    #pragma unroll
    for (int kc = 0; kc < NKC; ++kc) {
        U8 a;
        const int kb = kc * 32 + 4 * q;
        if (AF32) {
            const float* A = (const float*)Av + (size_t)row * K;
            f32x4 lo = (f32x4){0.f,0.f,0.f,0.f}, hi = (f32x4){0.f,0.f,0.f,0.f};
            if (kb < K)      lo = *(const f32x4*)(A + kb);
            if (kb + 16 < K) hi = *(const f32x4*)(A + kb + 16);
            #pragma unroll
            for (int i = 0; i < 4; ++i) {
                a.s[i]     = (short)f2bf(lo[i]);
                a.s[4 + i] = (short)f2bf(hi[i]);
            }
        } else {
            const u16* A = (const u16*)Av + (size_t)row * K;
            a.u[0] = (kb < K)      ? *(const u64*)(A + kb)      : 0ull;
            a.u[1] = (kb + 16 < K) ? *(const u64*)(A + kb + 16) : 0ull;
        }
        #pragma unroll
        for (int ct = 0; ct < 8; ++ct)
            acc[ct] = __builtin_amdgcn_mfma_f32_16x16x32_bf16(
                          a.v, wf[(kc * 8 + ct) * 64 + l], acc[ct], 0, 0, 0);
    }

    // C/D layout (HW-verified): col = lane&15, row = (lane>>4)*4 + reg
    const int orow0 = blockIdx.x * 64 + w * 16 + 4 * q;
    #pragma unroll
    for (int ct = 0; ct < 8; ++ct) {
        const int col = ct * 16 + lr;
        const float b = bias[col];
        #pragma unroll
        for (int r = 0; r < 4; ++r) {
            float v = acc[ct][r] + b;
            if (RELU) v = fmaxf(v, 0.f);
            if (OUTF32) ((float*)Cv)[(size_t)(orow0 + r) * 128 + col] = v;
            else        ((u16*)Cv)[(size_t)(orow0 + r) * 128 + col] = f2bf(v);
        }
    }
}

// ---------------- bf16 neighborhood aggregation ----------------
template<bool KW_SIDE>
__global__ __launch_bounds__(256) void aggb_k(
        const int* __restrict__ off, const int* __restrict__ cnt,
        const int* __restrict__ csr, const u16* __restrict__ gsrc,
        const u16* __restrict__ h0, const float* __restrict__ dis,
        u16* __restrict__ outb) {
    int r    = blockIdx.x * 8 + (threadIdx.x >> 5);
    int lane = threadIdx.x & 31;
    int seg  = KW_SIDE ? r : (NKW + r);
    int st = off[seg];
    int n  = cnt[seg];
    float a0 = 0.f, a1 = 0.f, a2 = 0.f, a3 = 0.f;
    #define ACC4(vv) { a0 += bf2f((u16)(vv)); a1 += bf2f((u16)((vv) >> 16)); \
                       a2 += bf2f((u16)((vv) >> 32)); a3 += bf2f((u16)((vv) >> 48)); }
    int i = 0;
    for (; i + 4 <= n; i += 4) {
        int nb0 = csr[st + i], nb1 = csr[st + i + 1];
        int nb2 = csr[st + i + 2], nb3 = csr[st + i + 3];
        u64 v0 = *(const u64*)(gsrc + (size_t)nb0 * 128 + lane * 4);
        u64 v1 = *(const u64*)(gsrc + (size_t)nb1 * 128 + lane * 4);
        u64 v2 = *(const u64*)(gsrc + (size_t)nb2 * 128 + lane * 4);
        u64 v3 = *(const u64*)(gsrc + (size_t)nb3 * 128 + lane * 4);
        ACC4(v0) ACC4(v1) ACC4(v2) ACC4(v3)
    }
    for (; i < n; ++i) {
        int nb = csr[st + i];
        u64 v = *(const u64*)(gsrc + (size_t)nb * 128 + lane * 4);
        ACC4(v)
    }
    #undef ACC4
    float dk = dis[seg];
    if (KW_SIDE) {   // t = dk*(sum + dk*h0)
        u64 h = *(const u64*)(h0 + (size_t)r * 128 + lane * 4);
        a0 = dk * (a0 + dk * bf2f((u16)h));
        a1 = dk * (a1 + dk * bf2f((u16)(h >> 16)));
        a2 = dk * (a2 + dk * bf2f((u16)(h >> 32)));
        a3 = dk * (a3 + dk * bf2f((u16)(h >> 48)));
    } else {         // pre-scale by dis_doc (commutes with the GEMM)
        a0 *= dk; a1 *= dk; a2 *= dk; a3 *= dk;
    }
    u64 ov = (u64)f2bf(a0) | ((u64)f2bf(a1) << 16) |
             ((u64)f2bf(a2) << 32) | ((u64)f2bf(a3) << 48);
    *(u64*)(outb + (size_t)r * 128 + lane * 4) = ov;
}

// ---------------- final gate: out_doc = xdoc * xf * xt (bf16 in, fp32 out) -------
__global__ void mulb_k(const u16* __restrict__ xd, const u16* __restrict__ xf,
                       const u16* __restrict__ xt, float* __restrict__ out) {
    size_t i = (size_t)blockIdx.x * 256 + threadIdx.x;    // group of 4 elems
    u64 d = ((const u64*)xd)[i];
    u64 f = ((const u64*)xf)[i];
    u64 t = ((const u64*)xt)[i];
    float4 o;
    o.x = bf2f((u16)d)         * bf2f((u16)f)         * bf2f((u16)t);
    o.y = bf2f((u16)(d >> 16)) * bf2f((u16)(f >> 16)) * bf2f((u16)(t >> 16));
    o.z = bf2f((u16)(d >> 32)) * bf2f((u16)(f >> 32)) * bf2f((u16)(t >> 32));
    o.w = bf2f((u16)(d >> 48)) * bf2f((u16)(f >> 48)) * bf2f((u16)(t >> 48));
    ((float4*)out)[i] = o;
}

extern "C" void kernel_launch(void* const* d_in, const int* in_sizes, int n_in,
                              void* d_out, int out_size, void* d_ws, size_t ws_size,
                              hipStream_t stream) {
    const float* Xn  = (const float*)d_in[0];
    const float* Xfb = (const float*)d_in[1];
    const float* Xt  = (const float*)d_in[2];
    const int*   e01 = (const int*)d_in[3];      // [2, E]: row0 src(kw), row1 dst(NKW+doc)
    const float* W0  = (const float*)d_in[6];
    const float* b0  = (const float*)d_in[7];
    const float* Wg1 = (const float*)d_in[8];
    const float* bg1 = (const float*)d_in[9];
    const float* Wg2 = (const float*)d_in[10];
    const float* bg2 = (const float*)d_in[11];
    const float* Wf1 = (const float*)d_in[12];
    const float* bf1 = (const float*)d_in[13];
    const float* Wf2 = (const float*)d_in[14];
    const float* bf2 = (const float*)d_in[15];
    const float* Wt1 = (const float*)d_in[16];
    const float* bt1 = (const float*)d_in[17];
    const float* Wt2 = (const float*)d_in[18];
    const float* bt2 = (const float*)d_in[19];

    float* out = (float*)d_out;
    char*  ws  = (char*)d_ws;
    u16*   bufA  = (u16*)(ws + BUFA_OFF);     // h0 bf16, later xf
    u32*   pairs = (u32*)(ws + BUFA_OFF);     // alias: dead before bufA first written
    u16*   bufB  = (u16*)(ws + BUFB_OFF);     // agg out bf16, later xt
    u16*   bufC  = (u16*)(ws + BUFC_OFF);     // xdoc bf16
    short8* wfb  = (short8*)(ws + WF_OFF);
    int*   csr   = (int*)(ws + CSR_OFF);
    int*   cnt   = (int*)(ws + CNT_OFF);
    int*   bhist = (int*)(ws + AUX_OFF);
    int*   bfill = bhist + 512;
    int*   bbase = bhist + 1024;
    int*   off   = (int*)(ws + OFF_OFF);
    float* dis   = (float*)(ws + DIS_OFF);

    const int* src = e01;
    const int* dst = e01 + NE;

    // weight pre-pack (independent)
    PrepArgs pa;
    pa.w[0] = W0;  pa.K[0] = 128;
    pa.w[1] = Wg1; pa.K[1] = 128;
    pa.w[2] = Wg2; pa.K[2] = 128;
    pa.w[3] = Wf1; pa.K[3] = 16;
    pa.w[4] = Wf2; pa.K[4] = 128;
    pa.w[5] = Wt1; pa.K[5] = 8;
    pa.w[6] = Wt2; pa.K[6] = 128;
    prepw_k<<<224, 64, 0, stream>>>(pa, wfb);

    // bucketed CSR build
    hipMemsetAsync(bhist, 0, 4096, stream);            // bhist + bfill
    bhist_k<<<NBLK, 256, 0, stream>>>(src, dst, bhist);
    bscan_k<<<1, 512, 0, stream>>>(bhist, bbase);
    part_k <<<NBLK, 256, 0, stream>>>(src, dst, bbase, bfill, pairs);
    build_k<<<512, 256, 0, stream>>>(pairs, bbase, bfill, off, cnt, dis, csr);

    // layer 0: h0 = relu(Xn[:NKW] @ W0 + b0)  (fp32 in, bf16 out) — overwrites pairs (dead)
    mgemm_k<128, true,  true,  false><<<1024, 256, 0, stream>>>(Xn, wfb + 0*2048, b0, bufA);

    // layer 1: aggB = dis_doc * sum h0[src] ; xdoc = relu(aggB @ Wg1 + bg1)
    aggb_k<false><<<NDOC / 8, 256, 0, stream>>>(off, cnt, csr, bufA, nullptr, dis, bufB);
    mgemm_k<128, false, true,  false><<<1024, 256, 0, stream>>>(bufB, wfb + 1*2048, bg1, bufC);

    // layer 2: aggB = dk*(sum xdoc[d] + dk*h0) ; out_kw = relu(aggB @ Wg2 + bg2) fp32
    aggb_k<true><<<NKW / 8, 256, 0, stream>>>(off, cnt, csr, bufC, bufA, dis, bufB);
    mgemm_k<128, false, true,  true ><<<1024, 256, 0, stream>>>(bufB, wfb + 2*2048, bg2, out);

    // gates (bufA free after layer-2 agg)
    mgemm_k<16,  true,  true,  false><<<1024, 256, 0, stream>>>(Xfb,  wfb + 3*2048, bf1, bufA);
    mgemm_k<128, false, false, false><<<1024, 256, 0, stream>>>(bufA, wfb + 4*2048, bf2, bufA); // in-place
    mgemm_k<8,   true,  true,  false><<<1024, 256, 0, stream>>>(Xt,   wfb + 5*2048, bt1, bufB);
    mgemm_k<128, false, false, false><<<1024, 256, 0, stream>>>(bufB, wfb + 6*2048, bt2, bufB); // in-place

    // out_doc = xdoc * xf * xt  (fp32 store)
    mulb_k<<<(NDOC * 128 / 4) / 256, 256, 0, stream>>>(bufC, bufA, bufB, out + (size_t)NKW * 128);
}

// Round 4
// 204.484 us; speedup vs baseline: 2.9972x; 1.1211x over previous
//
#include <hip/hip_runtime.h>

#define NKW   65536
#define NDOC  65536
#define NSEG  131072          // kw segs then doc segs
#define NE    1048576
#define CHUNK 4096            // edges per partition block
#define NBLK  (NE / CHUNK)    // 256

typedef unsigned long long u64;
typedef unsigned short     u16;
typedef unsigned int       u32;

typedef __attribute__((ext_vector_type(8))) short short8;   // 8 bf16 (4 VGPRs)
typedef __attribute__((ext_vector_type(4))) float f32x4;    // MFMA acc

union U8 { short8 v; u64 u[2]; short s[8]; };

__device__ __forceinline__ u16 f2bf(float f) {              // RNE f32->bf16
    u32 u = __builtin_bit_cast(u32, f);
    u = (u + 0x7fffu + ((u >> 16) & 1u)) >> 16;
    return (u16)u;
}
__device__ __forceinline__ float bf2f(u16 h) {
    return __builtin_bit_cast(float, (u32)h << 16);
}

// ---------------- workspace layout (bytes) ----------------
#define BUFA_OFF 0ull
#define BUFB_OFF 16777216ull
#define BUFC_OFF 33554432ull
#define WF_OFF   50331648ull            // 7 * 32KB fragment-packed weights
#define CSR_OFF  51380224ull            // 2*NE ints = 8 MB
#define CNT_OFF  59768832ull            // NSEG ints
#define AUX_OFF  60293120ull            // bhist[512] | bfill[512] | bbase[512]
#define OFF_OFF  60821504ull            // NSEG ints
#define DIS_OFF  61345792ull            // NSEG floats

// ---------------- CSR build (bucketed, write-local) ----------------
__global__ __launch_bounds__(256) void bhist_k(const int* __restrict__ src,
                                               const int* __restrict__ dst,
                                               int* __restrict__ bhist) {
    __shared__ int h[512];
    int tid = threadIdx.x;
    for (int i = tid; i < 512; i += 256) h[i] = 0;
    __syncthreads();
    int e0 = blockIdx.x * CHUNK;
    for (int i = tid; i < CHUNK; i += 256) {
        int s = src[e0 + i];
        int d = dst[e0 + i] - NKW;
        atomicAdd(&h[s >> 8], 1);
        atomicAdd(&h[256 + (d >> 8)], 1);
    }
    __syncthreads();
    for (int i = tid; i < 512; i += 256)
        if (h[i]) atomicAdd(&bhist[i], h[i]);
}

__global__ void bscan_k(const int* __restrict__ bhist, int* __restrict__ bbase) {
    __shared__ int s[512];
    int tid = threadIdx.x;
    int v = bhist[tid];
    s[tid] = v;
    __syncthreads();
    for (int d = 1; d < 512; d <<= 1) {
        int t = (tid >= d) ? s[tid - d] : 0;
        __syncthreads();
        s[tid] += t;
        __syncthreads();
    }
    bbase[tid] = s[tid] - v;      // exclusive
}

__global__ __launch_bounds__(256) void part_k(const int* __restrict__ src,
                                              const int* __restrict__ dst,
                                              const int* __restrict__ bbase,
                                              int* __restrict__ bfill,
                                              u32* __restrict__ pairs) {
    __shared__ int h[512], sc[512], base[512];
    __shared__ u32 staged[2 * CHUNK];
    const int tid = threadIdx.x;
    for (int i = tid; i < 512; i += 256) h[i] = 0;
    __syncthreads();

    const int e0 = blockIdx.x * CHUNK;
    int se[16], de[16];
    #pragma unroll
    for (int j = 0; j < 16; ++j) {
        int e = e0 + tid + j * 256;           // coalesced
        se[j] = src[e];
        de[j] = dst[e] - NKW;
        atomicAdd(&h[se[j] >> 8], 1);
        atomicAdd(&h[256 + (de[j] >> 8)], 1);
    }
    __syncthreads();

    sc[tid] = h[tid];
    __syncthreads();
    for (int d = 1; d < 256; d <<= 1) {
        int t = (tid >= d) ? sc[tid - d] : 0;
        __syncthreads();
        sc[tid] += t;
        __syncthreads();
    }
    sc[256 + tid] = h[256 + tid];
    __syncthreads();
    for (int d = 1; d < 256; d <<= 1) {
        int t = (tid >= d) ? sc[256 + tid - d] : 0;
        __syncthreads();
        sc[256 + tid] += t;
        __syncthreads();
    }

    for (int i = tid; i < 512; i += 256) {
        base[i] = bbase[i] + atomicAdd(&bfill[i], h[i]);
        sc[i] -= h[i];
        h[i] = 0;
    }
    __syncthreads();

    #pragma unroll
    for (int j = 0; j < 16; ++j) {
        int bk = se[j] >> 8;
        int r  = atomicAdd(&h[bk], 1);
        staged[sc[bk] + r] = ((u32)(se[j] & 255) << 16) | (u32)de[j];
        int bd = 256 + (de[j] >> 8);
        int r2 = atomicAdd(&h[bd], 1);
        staged[CHUNK + sc[bd] + r2] = ((u32)(de[j] & 255) << 16) | (u32)se[j];
    }
    __syncthreads();

    for (int i = tid; i < 512; i += 256) {
        int n = h[i];
        int so = (i < 256 ? 0 : CHUNK) + sc[i];
        u32* dp = pairs + base[i];
        for (int j = 0; j < n; ++j) dp[j] = staged[so + j];
    }
}

__global__ __launch_bounds__(256) void build_k(const u32* __restrict__ pairs,
                                               const int* __restrict__ bbase,
                                               const int* __restrict__ bfill,
                                               int* __restrict__ off, int* __restrict__ cnt,
                                               float* __restrict__ dis, int* __restrict__ csr) {
    __shared__ int lcnt[256], lsc[256];
    const int b   = blockIdx.x;
    const int tid = threadIdx.x;
    const int start = bbase[b];
    const int size  = bfill[b];
    lcnt[tid] = 0;
    __syncthreads();
    for (int i = tid; i < size; i += 256)
        atomicAdd(&lcnt[(pairs[start + i] >> 16) & 255], 1);
    __syncthreads();
    lsc[tid] = lcnt[tid];
    __syncthreads();
    for (int d = 1; d < 256; d <<= 1) {
        int t = (tid >= d) ? lsc[tid - d] : 0;
        __syncthreads();
        lsc[tid] += t;
        __syncthreads();
    }
    const int myexc = lsc[tid] - lcnt[tid];
    const int seg = (b < 256) ? (b * 256 + tid) : (NKW + (b - 256) * 256 + tid);
    off[seg] = start + myexc;
    cnt[seg] = lcnt[tid];
    dis[seg] = rsqrtf((float)(lcnt[tid] + 1));
    lsc[tid]  = myexc;
    lcnt[tid] = 0;
    __syncthreads();
    for (int i = tid; i < size; i += 256) {
        u32 p = pairs[start + i];
        int key = (p >> 16) & 255;
        int r = atomicAdd(&lcnt[key], 1);
        csr[start + lsc[key] + r] = (int)(p & 0xFFFF);
    }
}

// ---------------- weight fragment pre-pack (fp32 [K][128] -> bf16 MFMA frags) ----
// out[m*2048 + (kc*8+ct)*64 + lane] elem i: k = kc*32+4*(lane>>4)+(i&3)+16*(i>>2),
// col = ct*16 + (lane&15).  Serves as B-frag (col=n) AND swapped A-frag (col=m).
struct PrepArgs { const float* w[7]; int K[7]; };

__global__ void prepw_k(PrepArgs pa, short8* __restrict__ outb) {
    int m  = blockIdx.x >> 5;
    int bk = blockIdx.x & 31;
    int kc = bk >> 3, ct = bk & 7;
    int l  = threadIdx.x;
    int K  = pa.K[m];
    const float* W = pa.w[m];
    U8 o;
    #pragma unroll
    for (int i = 0; i < 8; ++i) {
        int k   = kc * 32 + 4 * (l >> 4) + (i & 3) + 16 * (i >> 2);
        int col = ct * 16 + (l & 15);
        float v = (k < K) ? W[(size_t)k * 128 + col] : 0.f;
        o.s[i] = (short)f2bf(v);
    }
    outb[(size_t)m * 2048 + bk * 64 + l] = o.v;
}

// ---------------- MFMA GEMM: C[65536,128] = op(A[65536,K] @ W[K,128] + b) --------
template<int K, bool AF32, bool RELU, bool OUTF32>
__global__ __launch_bounds__(256) void mgemm_k(
        const void* __restrict__ Av, const short8* __restrict__ wf,
        const float* __restrict__ bias, void* __restrict__ Cv) {
    const int tid = threadIdx.x;
    const int w  = tid >> 6;
    const int l  = tid & 63;
    const int lr = l & 15;
    const int q  = l >> 4;
    const int row = blockIdx.x * 64 + w * 16 + lr;
    constexpr int NKC = (K + 31) / 32;

    f32x4 acc[8];
    #pragma unroll
    for (int ct = 0; ct < 8; ++ct) acc[ct] = (f32x4){0.f, 0.f, 0.f, 0.f};

    #pragma unroll
    for (int kc = 0; kc < NKC; ++kc) {
        U8 a;
        const int kb = kc * 32 + 4 * q;
        if (AF32) {
            const float* A = (const float*)Av + (size_t)row * K;
            f32x4 lo = (f32x4){0.f,0.f,0.f,0.f}, hi = (f32x4){0.f,0.f,0.f,0.f};
            if (kb < K)      lo = *(const f32x4*)(A + kb);
            if (kb + 16 < K) hi = *(const f32x4*)(A + kb + 16);
            #pragma unroll
            for (int i = 0; i < 4; ++i) {
                a.s[i]     = (short)f2bf(lo[i]);
                a.s[4 + i] = (short)f2bf(hi[i]);
            }
        } else {
            const u16* A = (const u16*)Av + (size_t)row * K;
            a.u[0] = (kb < K)      ? *(const u64*)(A + kb)      : 0ull;
            a.u[1] = (kb + 16 < K) ? *(const u64*)(A + kb + 16) : 0ull;
        }
        #pragma unroll
        for (int ct = 0; ct < 8; ++ct)
            acc[ct] = __builtin_amdgcn_mfma_f32_16x16x32_bf16(
                          a.v, wf[(kc * 8 + ct) * 64 + l], acc[ct], 0, 0, 0);
    }

    const int orow0 = blockIdx.x * 64 + w * 16 + 4 * q;
    #pragma unroll
    for (int ct = 0; ct < 8; ++ct) {
        const int col = ct * 16 + lr;
        const float b = bias[col];
        #pragma unroll
        for (int r = 0; r < 4; ++r) {
            float v = acc[ct][r] + b;
            if (RELU) v = fmaxf(v, 0.f);
            if (OUTF32) ((float*)Cv)[(size_t)(orow0 + r) * 128 + col] = v;
            else        ((u16*)Cv)[(size_t)(orow0 + r) * 128 + col] = f2bf(v);
        }
    }
}

// ---------------- bf16 neighborhood aggregation (16 lanes/row, 16B/lane) --------
// Batch 16 csr indices (coalesced), broadcast via shfl(w=16); up to 16
// outstanding 16B gathers per lane.
template<bool KW_SIDE>
__global__ __launch_bounds__(256) void aggb_k(
        const int* __restrict__ off, const int* __restrict__ cnt,
        const int* __restrict__ csr, const u16* __restrict__ gsrc,
        const u16* __restrict__ h0, const float* __restrict__ dis,
        u16* __restrict__ outb) {
    const int r    = blockIdx.x * 16 + (threadIdx.x >> 4);
    const int lane = threadIdx.x & 15;
    const int seg  = KW_SIDE ? r : (NKW + r);
    const int st = off[seg];
    const int n  = cnt[seg];
    float a[8];
    #pragma unroll
    for (int j = 0; j < 8; ++j) a[j] = 0.f;

    #define EDGE(IDX) { \
        int nb = __shfl(nbv, (IDX), 16); \
        U8 v; v.v = *(const short8*)(gsrc + (size_t)nb * 128 + lane * 8); \
        _Pragma("unroll") \
        for (int j = 0; j < 8; ++j) a[j] += bf2f((u16)v.s[j]); }

    for (int i = 0; i < n; i += 16) {
        int m = n - i;
        int nbv = csr[st + i + (lane < m ? lane : 0)];
        if (m >= 16) {
            #pragma unroll
            for (int k = 0; k < 16; ++k) EDGE(k)
        } else {
            for (int k = 0; k < m; ++k) EDGE(k)
        }
    }
    #undef EDGE

    const float dk = dis[seg];
    if (KW_SIDE) {   // t = dk*(sum + dk*h0)
        U8 h; h.v = *(const short8*)(h0 + (size_t)r * 128 + lane * 8);
        #pragma unroll
        for (int j = 0; j < 8; ++j) a[j] = dk * (a[j] + dk * bf2f((u16)h.s[j]));
    } else {         // pre-scale by dis_doc (commutes with the GEMM)
        #pragma unroll
        for (int j = 0; j < 8; ++j) a[j] *= dk;
    }
    U8 o;
    #pragma unroll
    for (int j = 0; j < 8; ++j) o.s[j] = (short)f2bf(a[j]);
    *(short8*)(outb + (size_t)r * 128 + lane * 8) = o.v;
}

// ---------------- fused gates: out_doc = xdoc * xf * xt ----------------
// xf = relu(Xfb@Wf1+bf1)@Wf2+bf2 ; xt = relu(Xt@Wt1+bt1)@Wt2+bt2 — all in registers.
// Stage1 swapped (A=W1 frags, B=X^T frags) puts each doc-row's 128 channels
// lane-local: chan = mt*16 + 4q + reg -> stage2 A-frag[kc] elem i = tile 2kc+(i>>2), reg i&3.
__global__ __launch_bounds__(256) void gates_k(
        const float* __restrict__ Xfb, const float* __restrict__ Xt,
        const short8* __restrict__ wf1, const short8* __restrict__ wf2,
        const short8* __restrict__ wt1, const short8* __restrict__ wt2,
        const float* __restrict__ bf1v, const float* __restrict__ bf2v,
        const float* __restrict__ bt1v, const float* __restrict__ bt2v,
        const u16* __restrict__ xdoc, float* __restrict__ outdoc) {
    const int tid = threadIdx.x;
    const int w = tid >> 6, l = tid & 63, lr = l & 15, q = l >> 4;
    const int row0 = blockIdx.x * 64 + w * 16;      // wave's 16 doc rows

    f32x4 accf[8], acct[8];

    // ===== feedback gate =====
    {
        U8 bfrag;
        f32x4 x = *(const f32x4*)(Xfb + (size_t)(row0 + lr) * 16 + 4 * q);
        #pragma unroll
        for (int i = 0; i < 4; ++i) { bfrag.s[i] = (short)f2bf(x[i]); bfrag.s[4+i] = 0; }
        f32x4 s1[8];
        #pragma unroll
        for (int mt = 0; mt < 8; ++mt) {
            s1[mt] = __builtin_amdgcn_mfma_f32_16x16x32_bf16(
                         wf1[mt * 64 + l], bfrag.v, (f32x4){0.f,0.f,0.f,0.f}, 0, 0, 0);
            f32x4 bb = *(const f32x4*)(bf1v + mt * 16 + 4 * q);
            #pragma unroll
            for (int rr = 0; rr < 4; ++rr) s1[mt][rr] = fmaxf(s1[mt][rr] + bb[rr], 0.f);
        }
        #pragma unroll
        for (int ct = 0; ct < 8; ++ct) accf[ct] = (f32x4){0.f,0.f,0.f,0.f};
        #pragma unroll
        for (int kc = 0; kc < 4; ++kc) {
            U8 af;
            #pragma unroll
            for (int i = 0; i < 8; ++i) af.s[i] = (short)f2bf(s1[2*kc + (i>>2)][i & 3]);
            #pragma unroll
            for (int ct = 0; ct < 8; ++ct)
                accf[ct] = __builtin_amdgcn_mfma_f32_16x16x32_bf16(
                               af.v, wf2[(kc * 8 + ct) * 64 + l], accf[ct], 0, 0, 0);
        }
    }
    // ===== time gate =====
    {
        U8 bfrag;
        #pragma unroll
        for (int i = 0; i < 8; ++i) bfrag.s[i] = 0;
        if (q < 2) {
            f32x4 x = *(const f32x4*)(Xt + (size_t)(row0 + lr) * 8 + 4 * q);
            #pragma unroll
            for (int i = 0; i < 4; ++i) bfrag.s[i] = (short)f2bf(x[i]);
        }
        f32x4 s1[8];
        #pragma unroll
        for (int mt = 0; mt < 8; ++mt) {
            s1[mt] = __builtin_amdgcn_mfma_f32_16x16x32_bf16(
                         wt1[mt * 64 + l], bfrag.v, (f32x4){0.f,0.f,0.f,0.f}, 0, 0, 0);
            f32x4 bb = *(const f32x4*)(bt1v + mt * 16 + 4 * q);
            #pragma unroll
            for (int rr = 0; rr < 4; ++rr) s1[mt][rr] = fmaxf(s1[mt][rr] + bb[rr], 0.f);
        }
        #pragma unroll
        for (int ct = 0; ct < 8; ++ct) acct[ct] = (f32x4){0.f,0.f,0.f,0.f};
        #pragma unroll
        for (int kc = 0; kc < 4; ++kc) {
            U8 af;
            #pragma unroll
            for (int i = 0; i < 8; ++i) af.s[i] = (short)f2bf(s1[2*kc + (i>>2)][i & 3]);
            #pragma unroll
            for (int ct = 0; ct < 8; ++ct)
                acct[ct] = __builtin_amdgcn_mfma_f32_16x16x32_bf16(
                               af.v, wt2[(kc * 8 + ct) * 64 + l], acct[ct], 0, 0, 0);
        }
    }
    // ===== epilogue: out = xdoc * xf * xt =====
    const int orow0 = row0 + 4 * q;
    #pragma unroll
    for (int ct = 0; ct < 8; ++ct) {
        const int col = ct * 16 + lr;
        const float b2f = bf2v[col];
        const float b2t = bt2v[col];
        #pragma unroll
        for (int rr = 0; rr < 4; ++rr) {
            const size_t idx = (size_t)(orow0 + rr) * 128 + col;
            float xd = bf2f(xdoc[idx]);
            outdoc[idx] = xd * (accf[ct][rr] + b2f) * (acct[ct][rr] + b2t);
        }
    }
}

extern "C" void kernel_launch(void* const* d_in, const int* in_sizes, int n_in,
                              void* d_out, int out_size, void* d_ws, size_t ws_size,
                              hipStream_t stream) {
    const float* Xn  = (const float*)d_in[0];
    const float* Xfb = (const float*)d_in[1];
    const float* Xt  = (const float*)d_in[2];
    const int*   e01 = (const int*)d_in[3];
    const float* W0  = (const float*)d_in[6];
    const float* b0  = (const float*)d_in[7];
    const float* Wg1 = (const float*)d_in[8];
    const float* bg1 = (const float*)d_in[9];
    const float* Wg2 = (const float*)d_in[10];
    const float* bg2 = (const float*)d_in[11];
    const float* Wf1 = (const float*)d_in[12];
    const float* bf1 = (const float*)d_in[13];
    const float* Wf2 = (const float*)d_in[14];
    const float* bf2 = (const float*)d_in[15];
    const float* Wt1 = (const float*)d_in[16];
    const float* bt1 = (const float*)d_in[17];
    const float* Wt2 = (const float*)d_in[18];
    const float* bt2 = (const float*)d_in[19];

    float* out = (float*)d_out;
    char*  ws  = (char*)d_ws;
    u16*   bufA  = (u16*)(ws + BUFA_OFF);     // h0 bf16
    u32*   pairs = (u32*)(ws + BUFA_OFF);     // alias: dead before bufA first written
    u16*   bufB  = (u16*)(ws + BUFB_OFF);     // agg out bf16
    u16*   bufC  = (u16*)(ws + BUFC_OFF);     // xdoc bf16
    short8* wfb  = (short8*)(ws + WF_OFF);
    int*   csr   = (int*)(ws + CSR_OFF);
    int*   cnt   = (int*)(ws + CNT_OFF);
    int*   bhist = (int*)(ws + AUX_OFF);
    int*   bfill = bhist + 512;
    int*   bbase = bhist + 1024;
    int*   off   = (int*)(ws + OFF_OFF);
    float* dis   = (float*)(ws + DIS_OFF);

    const int* src = e01;
    const int* dst = e01 + NE;

    PrepArgs pa;
    pa.w[0] = W0;  pa.K[0] = 128;
    pa.w[1] = Wg1; pa.K[1] = 128;
    pa.w[2] = Wg2; pa.K[2] = 128;
    pa.w[3] = Wf1; pa.K[3] = 16;
    pa.w[4] = Wf2; pa.K[4] = 128;
    pa.w[5] = Wt1; pa.K[5] = 8;
    pa.w[6] = Wt2; pa.K[6] = 128;
    prepw_k<<<224, 64, 0, stream>>>(pa, wfb);

    // bucketed CSR build
    hipMemsetAsync(bhist, 0, 4096, stream);
    bhist_k<<<NBLK, 256, 0, stream>>>(src, dst, bhist);
    bscan_k<<<1, 512, 0, stream>>>(bhist, bbase);
    part_k <<<NBLK, 256, 0, stream>>>(src, dst, bbase, bfill, pairs);
    build_k<<<512, 256, 0, stream>>>(pairs, bbase, bfill, off, cnt, dis, csr);

    // layer 0: h0 = relu(Xn[:NKW] @ W0 + b0)
    mgemm_k<128, true,  true,  false><<<1024, 256, 0, stream>>>(Xn, wfb + 0*2048, b0, bufA);

    // layer 1: aggB = dis_doc * sum h0[src] ; xdoc = relu(aggB @ Wg1 + bg1)
    aggb_k<false><<<NDOC / 16, 256, 0, stream>>>(off, cnt, csr, bufA, nullptr, dis, bufB);
    mgemm_k<128, false, true,  false><<<1024, 256, 0, stream>>>(bufB, wfb + 1*2048, bg1, bufC);

    // layer 2: aggB = dk*(sum xdoc[d] + dk*h0) ; out_kw = relu(aggB @ Wg2 + bg2) fp32
    aggb_k<true><<<NKW / 16, 256, 0, stream>>>(off, cnt, csr, bufC, bufA, dis, bufB);
    mgemm_k<128, false, true,  true ><<<1024, 256, 0, stream>>>(bufB, wfb + 2*2048, bg2, out);

    // fused gates + final multiply (reads xdoc=bufC)
    gates_k<<<1024, 256, 0, stream>>>(Xfb, Xt,
                                      wfb + 3*2048, wfb + 4*2048, wfb + 5*2048, wfb + 6*2048,
                                      bf1, bf2, bt1, bt2,
                                      bufC, out + (size_t)NKW * 128);
}